// Round 9
// baseline (307.548 us; speedup 1.0000x reference)
//
#include <hip/hip_runtime.h>

typedef __attribute__((ext_vector_type(8))) short bf16x8;
typedef __attribute__((ext_vector_type(4))) float f32x4;

#define BB 1024
#define TT 256
#define DD 63
#define HH 128
#define CHUNK 4    // 4 batch rows/block, grid 256 = 1 block/CU
#define HSTR 160   // shorts; 80 dwords ≡ 16 (mod 32): broadcast b128 reads exactly 2-way (free)
#define XSTR 96    // shorts; 48 dwords ≡ 16 (mod 32)

// Barrier that drains only LDS (lgkmcnt), NOT outstanding global loads.
#define LDS_BARRIER() asm volatile("s_waitcnt lgkmcnt(0)\n\ts_barrier" ::: "memory")

__device__ __forceinline__ short f2bf(float f) {
  unsigned u = __builtin_bit_cast(unsigned, f);
  u = (u + 0x7FFFu + ((u >> 16) & 1u)) >> 16;   // RNE
  return (short)u;
}
__device__ __forceinline__ float sigm(float x) {
  return __builtin_amdgcn_rcpf(1.f + __expf(-x));
}
__device__ __forceinline__ float tanh_fast(float x) {
  float e = __expf(2.f * x);
  return 1.f - 2.f * __builtin_amdgcn_rcpf(e + 1.f);
}

// R9 = R8 (transposed GEMM + duplicate-group, 1 elem/lane, one lgkm-only
// barrier/step) with the x pipeline rebalanced:
//  - x staging split across ALL 8 waves (wave w: row w&3, col-half w>>2,
//    32 consecutive floats) -> no systematic barrier skew from waves 0-3
//    carrying all the global-memory work (R8: tid<252 only).
//  - store-BEFORE-load order: consume xv_pend (1 full step old -> complete)
//    before issuing x(t+2); a conservative s_waitcnt vmcnt(0) at the store
//    can no longer stall on a just-issued load.
//  - B-frag ds_reads issued first so any residual vmcnt wait hides under
//    their latency.
// Kept: launch_bounds min-waves=2 (R4: 4 => VGPR clamp => weight spill);
// grid=256 = 1 block/CU (R5: no 2-block co-residency); HSTR=160/XSTR=96
// (R7's 136 caused 4-8-way conflicts).
__global__ __launch_bounds__(512, 2)
void lstm_fwd_kernel(const float* __restrict__ X,
                     const float* __restrict__ Wih,
                     const float* __restrict__ Whh,
                     const float* __restrict__ bih,
                     const float* __restrict__ bhh,
                     const float* __restrict__ Wfc,
                     float* __restrict__ out) {
  __shared__ __align__(16) short hbuf[2 * 4 * HSTR];   // h^T (bf16), rows=batch 0..3, dbuf
  __shared__ __align__(16) short xbuf[2 * 4 * XSTR];   // x^T (bf16), rows=batch 0..3, 2 slots
  __shared__ __align__(16) float fst[4 * HH];          // epilogue h_f staging

  const int tid  = threadIdx.x;
  const int wave = tid >> 6;
  const int lane = tid & 63;
  const int quad = lane >> 4;
  const int l15  = lane & 15;
  const int b0   = blockIdx.x * CHUNK;
  const int br   = l15 & 3;        // this lane's batch row
  const int p    = l15 >> 2;       // duplicate-group index = accumulator reg to keep

  // ---- register-resident W fragments as MFMA A operands ----
  bf16x8 Ah[4][4];   // [gate][kstep], W_hh
  bf16x8 Axw[4][2];  // [gate][kstep], W_ih (K padded 63->64)
  f32x4  bias[4];    // bias per acc reg q: col = wave*16 + quad*4 + q
#pragma unroll
  for (int g = 0; g < 4; ++g) {
    const int n = g * 128 + wave * 16 + l15;
    const float* wr = Whh + (size_t)n * HH;
#pragma unroll
    for (int ks = 0; ks < 4; ++ks) {
      const int k0 = ks * 32 + quad * 8;
      f32x4 w0 = *(const f32x4*)(wr + k0);
      f32x4 w1 = *(const f32x4*)(wr + k0 + 4);
      bf16x8 v;
#pragma unroll
      for (int jj = 0; jj < 4; ++jj) { v[jj] = f2bf(w0[jj]); v[4 + jj] = f2bf(w1[jj]); }
      Ah[g][ks] = v;
    }
    const float* xr = Wih + (size_t)n * DD;
#pragma unroll
    for (int ks = 0; ks < 2; ++ks) {
      const int k0 = ks * 32 + quad * 8;
      bf16x8 v;
#pragma unroll
      for (int jj = 0; jj < 8; ++jj) {
        const int k = k0 + jj;
        v[jj] = (k < DD) ? f2bf(xr[k]) : (short)0;
      }
      Axw[g][ks] = v;
    }
    const int cb = g * 128 + wave * 16 + quad * 4;
    f32x4 b1 = *(const f32x4*)&bih[cb];
    f32x4 b2 = *(const f32x4*)&bhh[cb];
    bias[g] = b1 + b2;
  }

  // zero h buffers (h(0)=0) and x pad columns (both slots)
  for (int i = tid; i < 2 * 4 * HSTR; i += 512) hbuf[i] = 0;
  for (int i = tid; i < 2 * 4 * XSTR; i += 512) xbuf[i] = 0;

  // ---- balanced x staging: wave w -> row w&3, col-half w>>2 ----
  const int xrow  = wave & 3;
  const int xd    = (wave >> 2) * 32 + (lane & 31);
  const bool xthr = (lane < 32) && (xd < DD);
  const float* xptr = X + ((size_t)(b0 + xrow) * TT) * DD + xd;
  float xv_pend = 0.f;
  __syncthreads();                 // zero-fill visible before seeding slot 0
  if (xthr) {
    xbuf[xrow * XSTR + xd] = f2bf(xptr[0]);   // slot 0 = x(0)
    xv_pend = xptr[DD];                        // x(1)
    xptr += 2 * DD;                            // points at x(t+2) for t=0
  }
  __syncthreads();

  float cc = 0.f, hv = 0.f;   // ONE element per lane: (batch=br, col=wave*16+quad*4+p)
  const int hcol = wave * 16 + quad * 4 + p;

  for (int t = 0; t < TT; ++t) {
    const int xcur = (t & 1) * (4 * XSTR);
    const int hcur = (t & 1) * (4 * HSTR);

    // B-fragments first: start their latency immediately after the barrier
    bf16x8 Bh_[4], Bx_[2];
#pragma unroll
    for (int ks = 0; ks < 4; ++ks)
      Bh_[ks] = *(const bf16x8*)&hbuf[hcur + br * HSTR + ks * 32 + quad * 8];
#pragma unroll
    for (int ks = 0; ks < 2; ++ks)
      Bx_[ks] = *(const bf16x8*)&xbuf[xcur + br * XSTR + ks * 32 + quad * 8];

    // consume xv_pend (loaded one FULL step ago -> complete; vmcnt wait free),
    // writing x(t+1) into the slot not being read this step
    if (xthr && (t + 1 < TT))
      xbuf[(xcur ^ (4 * XSTR)) + xrow * XSTR + xd] = f2bf(xv_pend);
    // then issue x(t+2); stays in flight across the lgkm-only barrier
    float xv_new = 0.f;
    if (xthr && (t + 2 < TT)) { xv_new = *xptr; xptr += DD; }
    xv_pend = xv_new;

    // ---- MFMA: acc[g] = bias[g] + W_g @ [h;x]^T (4 independent chains) ----
    f32x4 acc[4];
#pragma unroll
    for (int g = 0; g < 4; ++g)
      acc[g] = __builtin_amdgcn_mfma_f32_16x16x32_bf16(Ah[g][0], Bh_[0], bias[g], 0, 0, 0);
#pragma unroll
    for (int ks = 1; ks < 4; ++ks)
#pragma unroll
      for (int g = 0; g < 4; ++g)
        acc[g] = __builtin_amdgcn_mfma_f32_16x16x32_bf16(Ah[g][ks], Bh_[ks], acc[g], 0, 0, 0);
#pragma unroll
    for (int ks = 0; ks < 2; ++ks)
#pragma unroll
      for (int g = 0; g < 4; ++g)
        acc[g] = __builtin_amdgcn_mfma_f32_16x16x32_bf16(Axw[g][ks], Bx_[ks], acc[g], 0, 0, 0);

    // ---- select register p (2 v_cmp + 12 cndmask), elementwise 1 elem/lane ----
    const bool s0 = (l15 & 4) != 0;
    const bool s1 = (l15 & 8) != 0;
    float gv4[4];
#pragma unroll
    for (int g = 0; g < 4; ++g) {
      const float a01 = s0 ? acc[g][1] : acc[g][0];
      const float a23 = s0 ? acc[g][3] : acc[g][2];
      gv4[g] = s1 ? a23 : a01;
    }
    const float iv = sigm(gv4[0]);
    const float fv = sigm(gv4[1]);
    const float gg = tanh_fast(gv4[2]);
    const float ov = sigm(gv4[3]);
    cc = fv * cc + iv * gg;
    hv = ov * tanh_fast(cc);
    hbuf[(hcur ^ (4 * HSTR)) + br * HSTR + hcol] = f2bf(hv);

    LDS_BARRIER();   // the ONE barrier: h/x produced -> consumed next step
  }

  // ---- epilogue: forward half of FC (fp32, no bias) ----
  fst[br * HH + hcol] = hv;
  __syncthreads();
  if (tid < CHUNK * 14) {
    const int rr = tid / 14, o = tid - rr * 14;
    const float* wr = Wfc + (size_t)o * (2 * HH);
    float acc = 0.f;
#pragma unroll 16
    for (int k = 0; k < HH; ++k) acc += wr[k] * fst[rr * HH + k];
    out[(size_t)(b0 + rr) * 14 + o] = acc;
  }
}

// Backward direction collapses to ONE cell step on x[:,T-1] (h0=c0=0),
// done in exact fp32, plus the backward half of the FC (+ biases).
__global__ __launch_bounds__(256, 2)
void lstm_bwd_fc_kernel(const float* __restrict__ X,
                        const float* __restrict__ Wih_b,
                        const float* __restrict__ bih_b,
                        const float* __restrict__ bhh_b,
                        const float* __restrict__ Wfc,
                        const float* __restrict__ bfc,
                        float* __restrict__ out) {
  __shared__ float xl[DD];
  __shared__ float glb[4 * HH];
  __shared__ float hl[HH];
  __shared__ float pl[14 * 8];
  const int b = blockIdx.x;
  const int tid = threadIdx.x;

  if (tid < DD) xl[tid] = X[((size_t)b * TT + (TT - 1)) * DD + tid];
  __syncthreads();

#pragma unroll
  for (int u = 0; u < 2; ++u) {
    const int n = tid * 2 + u;
    const float* wr = Wih_b + (size_t)n * DD;
    float acc = bih_b[n] + bhh_b[n];
#pragma unroll
    for (int k = 0; k < DD; ++k) acc += wr[k] * xl[k];
    glb[n] = acc;
  }
  __syncthreads();

  if (tid < HH) {
    float iv = sigm(glb[0 * HH + tid]);
    float gv = tanh_fast(glb[2 * HH + tid]);
    float ov = sigm(glb[3 * HH + tid]);
    hl[tid] = ov * tanh_fast(iv * gv);   // c = f*0 + i*g
  }
  __syncthreads();

  if (tid < 14 * 8) {
    const int o = tid >> 3, kp = tid & 7;
    const float* wr = Wfc + (size_t)o * (2 * HH) + HH;
    float acc = 0.f;
#pragma unroll
    for (int i = 0; i < 16; ++i) {
      const int jj = kp * 16 + i;
      acc += wr[jj] * hl[jj];
    }
    pl[tid] = acc;
  }
  __syncthreads();

  if (tid < 14) {
    float acc = bfc[tid];
#pragma unroll
    for (int i = 0; i < 8; ++i) acc += pl[tid * 8 + i];
    out[(size_t)b * 14 + tid] += acc;   // add to forward partial
  }
}

extern "C" void kernel_launch(void* const* d_in, const int* in_sizes, int n_in,
                              void* d_out, int out_size, void* d_ws, size_t ws_size,
                              hipStream_t stream) {
  const float* X     = (const float*)d_in[0];
  const float* Wih_f = (const float*)d_in[1];
  const float* Whh_f = (const float*)d_in[2];
  const float* bih_f = (const float*)d_in[3];
  const float* bhh_f = (const float*)d_in[4];
  const float* Wih_b = (const float*)d_in[5];
  // d_in[6] = W_hh_b: unused (backward dir needs only one step from zero state)
  const float* bih_b = (const float*)d_in[7];
  const float* bhh_b = (const float*)d_in[8];
  const float* Wfc   = (const float*)d_in[9];
  const float* bfc   = (const float*)d_in[10];
  float* out = (float*)d_out;

  lstm_fwd_kernel<<<BB / CHUNK, 512, 0, stream>>>(X, Wih_f, Whh_f, bih_f, bhh_f, Wfc, out);
  lstm_bwd_fc_kernel<<<BB, 256, 0, stream>>>(X, Wih_b, bih_b, bhh_b, Wfc, bfc, out);
}

// Round 10
// 285.849 us; speedup vs baseline: 1.0759x; 1.0759x over previous
//
#include <hip/hip_runtime.h>

typedef __attribute__((ext_vector_type(8))) short bf16x8;
typedef __attribute__((ext_vector_type(4))) float f32x4;

#define BB 1024
#define TT 256
#define DD 63
#define HH 128
#define CHUNK 4    // 4 batch rows/block, grid 256 = 1 block/CU
#define HSTR 160   // shorts; 80 dwords ≡ 16 (mod 32): broadcast b128 reads exactly 2-way (free)
#define XSTR 96    // shorts; 48 dwords ≡ 16 (mod 32)
#define BWB 16     // bwd kernel: batches per block (W-reuse)

// Barrier that drains only LDS (lgkmcnt), NOT outstanding global loads.
#define LDS_BARRIER() asm volatile("s_waitcnt lgkmcnt(0)\n\ts_barrier" ::: "memory")

__device__ __forceinline__ short f2bf(float f) {
  unsigned u = __builtin_bit_cast(unsigned, f);
  u = (u + 0x7FFFu + ((u >> 16) & 1u)) >> 16;   // RNE
  return (short)u;
}
__device__ __forceinline__ float sigm(float x) {
  return __builtin_amdgcn_rcpf(1.f + __expf(-x));
}
__device__ __forceinline__ float tanh_fast(float x) {
  float e = __expf(2.f * x);
  return 1.f - 2.f * __builtin_amdgcn_rcpf(e + 1.f);
}

// R10 fwd = R8 (transposed GEMM + duplicate-group, 1 elem/lane, one lgkm-only
// barrier/step) with PER-GATE STAGGERED scheduling:
//   gate g's 6 MFMAs issue as one dependent chain, then g's select+activation
//   immediately — its trans ops overlap the NEXT gate's MFMA issue (R8/R9
//   ordered all-MFMA-then-all-VALU: pipes ran in sequence, 931+780 cyc/step).
// MFMA pipe floor per block-step: 192 MFMA x 4.85 cyc/CU = 931 cyc; goal is
// step -> 931 + ~150 tail instead of 1950.
// Kept: launch_bounds min-waves=2 (R4: VGPR clamp => weight spill); grid=256
// = 1 block/CU (R5); HSTR=160/XSTR=96 (R7: 136 => 4-8-way conflicts);
// R8 x staging (R9's "balanced" version measured slightly worse).
__global__ __launch_bounds__(512, 2)
void lstm_fwd_kernel(const float* __restrict__ X,
                     const float* __restrict__ Wih,
                     const float* __restrict__ Whh,
                     const float* __restrict__ bih,
                     const float* __restrict__ bhh,
                     const float* __restrict__ Wfc,
                     float* __restrict__ out) {
  __shared__ __align__(16) short hbuf[2 * 4 * HSTR];   // h^T (bf16), rows=batch 0..3, dbuf
  __shared__ __align__(16) short xbuf[2 * 4 * XSTR];   // x^T (bf16), rows=batch 0..3, 2 slots
  __shared__ __align__(16) float fst[4 * HH];          // epilogue h_f staging

  const int tid  = threadIdx.x;
  const int wave = tid >> 6;
  const int lane = tid & 63;
  const int quad = lane >> 4;
  const int l15  = lane & 15;
  const int b0   = blockIdx.x * CHUNK;
  const int br   = l15 & 3;        // this lane's batch row
  // duplicate-group index p = l15>>2 selects which acc register is valid

  // ---- register-resident W fragments as MFMA A operands ----
  bf16x8 Ah[4][4];   // [gate][kstep], W_hh
  bf16x8 Axw[4][2];  // [gate][kstep], W_ih (K padded 63->64)
  f32x4  bias[4];    // bias per acc reg q: col = wave*16 + quad*4 + q
#pragma unroll
  for (int g = 0; g < 4; ++g) {
    const int n = g * 128 + wave * 16 + l15;
    const float* wr = Whh + (size_t)n * HH;
#pragma unroll
    for (int ks = 0; ks < 4; ++ks) {
      const int k0 = ks * 32 + quad * 8;
      f32x4 w0 = *(const f32x4*)(wr + k0);
      f32x4 w1 = *(const f32x4*)(wr + k0 + 4);
      bf16x8 v;
#pragma unroll
      for (int jj = 0; jj < 4; ++jj) { v[jj] = f2bf(w0[jj]); v[4 + jj] = f2bf(w1[jj]); }
      Ah[g][ks] = v;
    }
    const float* xr = Wih + (size_t)n * DD;
#pragma unroll
    for (int ks = 0; ks < 2; ++ks) {
      const int k0 = ks * 32 + quad * 8;
      bf16x8 v;
#pragma unroll
      for (int jj = 0; jj < 8; ++jj) {
        const int k = k0 + jj;
        v[jj] = (k < DD) ? f2bf(xr[k]) : (short)0;
      }
      Axw[g][ks] = v;
    }
    const int cb = g * 128 + wave * 16 + quad * 4;
    f32x4 b1 = *(const f32x4*)&bih[cb];
    f32x4 b2 = *(const f32x4*)&bhh[cb];
    bias[g] = b1 + b2;
  }

  // zero h buffers (h(0)=0); x pad columns zeroed once (both slots)
  for (int i = tid; i < 2 * 4 * HSTR; i += 512) hbuf[i] = 0;
  if (tid >= CHUNK * DD && tid < 256) {
    const int rr = tid & 3;
    xbuf[rr * XSTR + DD] = 0;
    xbuf[4 * XSTR + rr * XSTR + DD] = 0;
  }

  // x staging (R8 mapping): 4 rows x 63 cols = 252 threads, distance-2
  const int xrow = tid / DD;
  const int xd   = tid - xrow * DD;
  const bool xthr = (tid < CHUNK * DD);
  const float* xptr = X + ((size_t)(b0 + xrow) * TT) * DD + xd;
  float xv_pend = 0.f;
  if (xthr) {
    xbuf[xrow * XSTR + xd] = f2bf(xptr[0]);   // slot 0 = x(0)
    xv_pend = xptr[DD];                        // x(1)
    xptr += 2 * DD;
  }
  __syncthreads();

  float cc = 0.f, hv = 0.f;   // ONE element per lane: (batch=br, col=wave*16+quad*4+p)
  const int hcol = wave * 16 + quad * 4 + (l15 >> 2);
  const bool s0 = (l15 & 4) != 0;
  const bool s1 = (l15 & 8) != 0;

  for (int t = 0; t < TT; ++t) {
    const int xcur = (t & 1) * (4 * XSTR);
    const int hcur = (t & 1) * (4 * HSTR);

    // issue x(t+2) early; stays in flight across the lgkm-only barrier
    float xv_new = 0.f;
    const bool pf2 = xthr && (t + 2 < TT);
    if (pf2) { xv_new = *xptr; xptr += DD; }

    // B-fragments: row br (l15&3) -> 4-way same-address broadcast, 2-way banks
    bf16x8 Bh_[4], Bx_[2];
#pragma unroll
    for (int ks = 0; ks < 4; ++ks)
      Bh_[ks] = *(const bf16x8*)&hbuf[hcur + br * HSTR + ks * 32 + quad * 8];
#pragma unroll
    for (int ks = 0; ks < 2; ++ks)
      Bx_[ks] = *(const bf16x8*)&xbuf[xcur + br * XSTR + ks * 32 + quad * 8];

    // ---- per-gate staggered: 6-MFMA dependent chain, then THAT gate's
    //      select+activation (overlaps the next gate's MFMA issue) ----
    float gact[4];
#pragma unroll
    for (int g = 0; g < 4; ++g) {
      f32x4 a = __builtin_amdgcn_mfma_f32_16x16x32_bf16(Ah[g][0], Bh_[0], bias[g], 0, 0, 0);
      a = __builtin_amdgcn_mfma_f32_16x16x32_bf16(Ah[g][1], Bh_[1], a, 0, 0, 0);
      a = __builtin_amdgcn_mfma_f32_16x16x32_bf16(Ah[g][2], Bh_[2], a, 0, 0, 0);
      a = __builtin_amdgcn_mfma_f32_16x16x32_bf16(Ah[g][3], Bh_[3], a, 0, 0, 0);
      a = __builtin_amdgcn_mfma_f32_16x16x32_bf16(Axw[g][0], Bx_[0], a, 0, 0, 0);
      a = __builtin_amdgcn_mfma_f32_16x16x32_bf16(Axw[g][1], Bx_[1], a, 0, 0, 0);
      const float a01 = s0 ? a[1] : a[0];
      const float a23 = s0 ? a[3] : a[2];
      const float v = s1 ? a23 : a01;
      gact[g] = (g == 2) ? tanh_fast(v) : sigm(v);
    }

    // ---- short exposed tail ----
    cc = gact[1] * cc + gact[0] * gact[2];
    hv = gact[3] * tanh_fast(cc);
    hbuf[(hcur ^ (4 * HSTR)) + br * HSTR + hcol] = f2bf(hv);

    if (xthr && (t + 1 < TT))
      xbuf[(xcur ^ (4 * XSTR)) + xrow * XSTR + xd] = f2bf(xv_pend);
    xv_pend = xv_new;
    LDS_BARRIER();   // the ONE barrier: h/x produced -> consumed next step
  }

  // ---- epilogue: forward half of FC (fp32, no bias) ----
  fst[br * HH + hcol] = hv;
  __syncthreads();
  if (tid < CHUNK * 14) {
    const int rr = tid / 14, o = tid - rr * 14;
    const float* wr = Wfc + (size_t)o * (2 * HH);
    float acc = 0.f;
#pragma unroll 16
    for (int k = 0; k < HH; ++k) acc += wr[k] * fst[rr * HH + k];
    out[(size_t)(b0 + rr) * 14 + o] = acc;
  }
}

// Backward direction = ONE cell step on x[:,T-1] (h0=c0=0) + bwd half of FC.
// R10: 16 batches per block (grid 64) so W_ih_b (129 KB) is read once per
// block, not once per batch — R9's version caused 132 MB of L2/L3 traffic
// (~95 us, measured as total-minus-fwd).
__global__ __launch_bounds__(256, 2)
void lstm_bwd_fc_kernel(const float* __restrict__ X,
                        const float* __restrict__ Wih_b,
                        const float* __restrict__ bih_b,
                        const float* __restrict__ bhh_b,
                        const float* __restrict__ Wfc,
                        const float* __restrict__ bfc,
                        float* __restrict__ out) {
  __shared__ float xl[BWB * 64];     // x_last, 16 x 63 (pad 64)
  __shared__ float glb[BWB * 512];   // gates [b][n]
  __shared__ float hl[BWB * HH];     // h_b last
  const int tid = threadIdx.x;
  const int b0  = blockIdx.x * BWB;

  for (int i = tid; i < BWB * DD; i += 256) {
    const int b = i / DD, k = i - b * DD;
    xl[b * 64 + k] = X[((size_t)(b0 + b) * TT + (TT - 1)) * DD + k];
  }
  __syncthreads();

  // gate pre-activations: thread n covers cols {n, n+256}; W row reused
  // across all 16 batches from registers
#pragma unroll
  for (int u = 0; u < 2; ++u) {
    const int n = tid + u * 256;
    const float* wr = Wih_b + (size_t)n * DD;
    const float bb = bih_b[n] + bhh_b[n];
    float accs[BWB];
#pragma unroll
    for (int b = 0; b < BWB; ++b) accs[b] = bb;
    for (int k = 0; k < DD; ++k) {
      const float w = wr[k];
#pragma unroll
      for (int b = 0; b < BWB; ++b) accs[b] += w * xl[b * 64 + k];
    }
#pragma unroll
    for (int b = 0; b < BWB; ++b) glb[b * 512 + n] = accs[b];
  }
  __syncthreads();

  // cell (f*c0 = 0): h = o * tanh(i*g)
#pragma unroll
  for (int u = 0; u < 8; ++u) {
    const int idx = tid + u * 256;           // 0..2047 = 16 b x 128 j
    const int b = idx >> 7, j = idx & 127;
    const float iv = sigm(glb[b * 512 + j]);
    const float gv = tanh_fast(glb[b * 512 + 256 + j]);
    const float ov = sigm(glb[b * 512 + 384 + j]);
    hl[b * HH + j] = ov * tanh_fast(iv * gv);
  }
  __syncthreads();

  // backward half of FC (+ bias), += onto forward partial (same stream)
  if (tid < BWB * 14) {
    const int b = tid / 14, o = tid - b * 14;
    const float* wr = Wfc + (size_t)o * (2 * HH) + HH;
    float acc = bfc[o];
#pragma unroll 16
    for (int k = 0; k < HH; ++k) acc += wr[k] * hl[b * HH + k];
    out[(size_t)(b0 + b) * 14 + o] += acc;
  }
}

extern "C" void kernel_launch(void* const* d_in, const int* in_sizes, int n_in,
                              void* d_out, int out_size, void* d_ws, size_t ws_size,
                              hipStream_t stream) {
  const float* X     = (const float*)d_in[0];
  const float* Wih_f = (const float*)d_in[1];
  const float* Whh_f = (const float*)d_in[2];
  const float* bih_f = (const float*)d_in[3];
  const float* bhh_f = (const float*)d_in[4];
  const float* Wih_b = (const float*)d_in[5];
  // d_in[6] = W_hh_b: unused (backward dir needs only one step from zero state)
  const float* bih_b = (const float*)d_in[7];
  const float* bhh_b = (const float*)d_in[8];
  const float* Wfc   = (const float*)d_in[9];
  const float* bfc   = (const float*)d_in[10];
  float* out = (float*)d_out;

  lstm_fwd_kernel<<<BB / CHUNK, 512, 0, stream>>>(X, Wih_f, Whh_f, bih_f, bhh_f, Wfc, out);
  lstm_bwd_fc_kernel<<<BB / BWB, 256, 0, stream>>>(X, Wih_b, bih_b, bhh_b, Wfc, bfc, out);
}